// Round 7
// baseline (329.075 us; speedup 1.0000x reference)
//
#include <hip/hip_runtime.h>
#include <hip/hip_bf16.h>
#include <stdint.h>

#define N_TOK 16384
#define D_IN  2048
#define D_HID 2048

typedef __attribute__((ext_vector_type(8))) short  bf16x8;
typedef __attribute__((ext_vector_type(4))) float  f32x4;
typedef __attribute__((ext_vector_type(8))) unsigned short u16x8;

__device__ __forceinline__ unsigned short f2bf(float f) {
    unsigned int u = __float_as_uint(f);
    u = (u + 0x7FFFu + ((u >> 16) & 1u)) >> 16;
    return (unsigned short)u;
}

// ---------------------------------------------------------------- gate ----
__global__ void gate_kernel(const float* __restrict__ x,
                            const float* __restrict__ Wg,
                            const float* __restrict__ bg,
                            float* __restrict__ s12,
                            int* __restrict__ eidx) {
    const int token = blockIdx.x * 4 + (threadIdx.x >> 6);
    const int lane  = threadIdx.x & 63;
    const float* xr = x + (size_t)token * D_IN;

    float acc[8];
#pragma unroll
    for (int e = 0; e < 8; ++e) acc[e] = 0.f;

    for (int i = lane; i < D_IN; i += 64) {
        float xv = xr[i];
        const float4* wr = (const float4*)(Wg + (size_t)i * 8);
        float4 w0 = wr[0], w1 = wr[1];
        acc[0] += xv * w0.x; acc[1] += xv * w0.y;
        acc[2] += xv * w0.z; acc[3] += xv * w0.w;
        acc[4] += xv * w1.x; acc[5] += xv * w1.y;
        acc[6] += xv * w1.z; acc[7] += xv * w1.w;
    }
#pragma unroll
    for (int off = 32; off > 0; off >>= 1) {
#pragma unroll
        for (int e = 0; e < 8; ++e) acc[e] += __shfl_xor(acc[e], off);
    }

    float lg[8];
    float mx = -1e30f;
#pragma unroll
    for (int e = 0; e < 8; ++e) { lg[e] = acc[e] + bg[e]; mx = fmaxf(mx, lg[e]); }
    float sum = 0.f;
#pragma unroll
    for (int e = 0; e < 8; ++e) { lg[e] = expf(lg[e] - mx); sum += lg[e]; }
    float inv = 1.f / sum;

    float s1 = -1.f, s2 = -1.f; int i1 = 0, i2 = 0;
#pragma unroll
    for (int e = 0; e < 8; ++e) {
        float g = lg[e] * inv;
        if (g > s1)      { s2 = s1; i2 = i1; s1 = g; i1 = e; }
        else if (g > s2) { s2 = g;  i2 = e; }
    }
    if (lane == 0) {
        s12[token * 2]     = s1;
        s12[token * 2 + 1] = s2;
        if (token == 0) { eidx[0] = i1; eidx[1] = i2; }
    }
}

// ------------------------------- x -> bf16, slab order (staging image) ----
__global__ __launch_bounds__(256) void xconv_kernel(
    const float* __restrict__ x, unsigned short* __restrict__ xb) {
    const int mt = blockIdx.x >> 6;
    const int kt = blockIdx.x & 63;
    const int t  = threadIdx.x;
    const float* src = x + ((size_t)(mt * 256 + t)) * D_IN + kt * 32;
    unsigned short* slab = xb + ((size_t)(mt * 64 + kt)) * 8192;
#pragma unroll
    for (int ks = 0; ks < 4; ++ks) {
        float4 a = *(const float4*)(src + ks * 8);
        float4 b = *(const float4*)(src + ks * 8 + 4);
        u16x8 v;
        v[0] = f2bf(a.x); v[1] = f2bf(a.y); v[2] = f2bf(a.z); v[3] = f2bf(a.w);
        v[4] = f2bf(b.x); v[5] = f2bf(b.y); v[6] = f2bf(b.z); v[7] = f2bf(b.w);
        *(u16x8*)(slab + (ks * 256 + t) * 8) = v;
    }
}

// --------------------- W[e0],W[e1] -> bf16 slab order (transposed) --------
__global__ void wconv_kernel(const float* __restrict__ W,
                             const int* __restrict__ eidx,
                             unsigned short* __restrict__ wbT) {
    __shared__ float tile[64][65];
    const int be  = blockIdx.z;
    const int e   = eidx[be];
    const int k0  = blockIdx.y * 64;
    const int n0  = blockIdx.x * 64;
    const int bx  = n0 >> 7;
    const int cl0 = n0 & 127;
    const int kt0 = k0 >> 5;
    const float* src = W + (size_t)e * D_IN * D_HID;
    const int t = threadIdx.x;

#pragma unroll
    for (int p = 0; p < 4; ++p) {
        int row = p * 16 + (t >> 4);
        int col = (t & 15) * 4;
        const float* s = src + (size_t)(k0 + row) * D_HID + n0 + col;
        tile[row][col]     = s[0];
        tile[row][col + 1] = s[1];
        tile[row][col + 2] = s[2];
        tile[row][col + 3] = s[3];
    }
    __syncthreads();

    const int g   = (t >> 5) * 8;
    const int ktl = t >> 7;
    const int ks  = (t >> 5) & 3;
#pragma unroll
    for (int p = 0; p < 2; ++p) {
        int n = p * 32 + (t & 31);
        u16x8 v;
#pragma unroll
        for (int j = 0; j < 8; ++j) v[j] = f2bf(tile[g + j][n]);
        unsigned short* dst = wbT + ((size_t)(bx * 64 + kt0 + ktl)) * 8192 +
                              ((size_t)(ks * 256 + be * 128 + cl0 + n)) * 8;
        *(u16x8*)dst = v;
    }
}

// ------------------------------------------------------------------ GEMM --
// 256 rows x (128 cols x 2 experts), BK=32, 4 LDS buffers, depth-3 staging,
// contiguous slab sources. Software-pipelined fragment reads: a4-7(t) read
// in PH1(t); b(t+1),a0-3(t+1) read in PH2(t) into the alternate register
// set. Each MFMA cluster gated only on reads issued one phase earlier.
// ONE barrier per K-tile (PH2 end). vmcnt(4) per tile keeps only tile
// t+3's 4 loads outstanding; fence chain: all-waves vmcnt(4)@PH2(t) ->
// barrier -> reads of t+2 @PH2(t+1).
#define GLD16(gp, lp)                                                        \
    __builtin_amdgcn_global_load_lds(                                        \
        (const __attribute__((address_space(1))) void*)(gp),                 \
        (__attribute__((address_space(3))) void*)(lp), 16, 0, 0)

#define LDSV(SLOT) (*(const bf16x8*)&lds[(SLOT) * 8])

#define STAGE_A(SBAS, KT)                                                    \
    do {                                                                     \
        GLD16(gA0 + (size_t)(KT) * 8192,        &lds[((SBAS) + t512) * 8]);  \
        GLD16(gA0 + (size_t)(KT) * 8192 + 4096, &lds[((SBAS) + 512 + t512) * 8]); \
    } while (0)
#define STAGE_B(SBAS, KT)                                                    \
    do {                                                                     \
        GLD16(gB0 + (size_t)(KT) * 8192,        &lds[((SBAS) + 1024 + t512) * 8]); \
        GLD16(gB0 + (size_t)(KT) * 8192 + 4096, &lds[((SBAS) + 1536 + t512) * 8]); \
    } while (0)

#define MF16(ASET, BSET, MB)                                                 \
    _Pragma("unroll")                                                        \
    for (int mi = 0; mi < 4; ++mi)                                           \
        _Pragma("unroll")                                                    \
        for (int ni = 0; ni < 4; ++ni)                                       \
            acc[(MB) + mi][ni] = __builtin_amdgcn_mfma_f32_16x16x32_bf16(    \
                ASET[mi], BSET[ni], acc[(MB) + mi][ni], 0, 0, 0);

// PH1(t): read a4-7(t); stage A(t+3); MFMA1 = a0-3(t) x b(t). No barrier.
#define PH1(TT, STG, AS, BS)                                                 \
    do {                                                                     \
        const int rb = ((TT) & 3) * 2048;                                    \
        a4[0] = LDSV(rb + aks + arow + 64);                                  \
        a4[1] = LDSV(rb + aks + arow + 80);                                  \
        a4[2] = LDSV(rb + aks + arow + 96);                                  \
        a4[3] = LDSV(rb + aks + arow + 112);                                 \
        if (STG) STAGE_A((((TT) + 3) & 3) * 2048, (TT) + 3);                 \
        __builtin_amdgcn_s_setprio(1);                                       \
        MF16(AS, BS, 0)                                                      \
        __builtin_amdgcn_s_setprio(0);                                       \
    } while (0)

// PH2(t): read b(t+1),a0-3(t+1) into next set; stage B(t+3); vmcnt; MFMA2 =
// a4-7(t) x b(t); barrier.
#define PH2(TT, STG, VMSTR, BN, AN, BC)                                      \
    do {                                                                     \
        const int rb = (((TT) + 1) & 3) * 2048;                              \
        BN[0] = LDSV(rb + 1024 + aks + brow);                                \
        BN[1] = LDSV(rb + 1024 + aks + brow + 16);                           \
        BN[2] = LDSV(rb + 1024 + aks + brow + 32);                           \
        BN[3] = LDSV(rb + 1024 + aks + brow + 48);                           \
        AN[0] = LDSV(rb + aks + arow);                                       \
        AN[1] = LDSV(rb + aks + arow + 16);                                  \
        AN[2] = LDSV(rb + aks + arow + 32);                                  \
        AN[3] = LDSV(rb + aks + arow + 48);                                  \
        if (STG) STAGE_B((((TT) + 3) & 3) * 2048, (TT) + 3);                 \
        asm volatile(VMSTR ::: "memory");                                    \
        __builtin_amdgcn_s_setprio(1);                                       \
        MF16(a4, BC, 4)                                                      \
        __builtin_amdgcn_s_setprio(0);                                       \
        __builtin_amdgcn_s_barrier();                                        \
    } while (0)

__global__ __launch_bounds__(512, 2) void moe_gemm_kernel(
    const unsigned short* __restrict__ xb,   // slab order [mt64][kt64][1024]
    const unsigned short* __restrict__ wbT,  // slab order [bx16][kt64][1024]
    const float* __restrict__ b_exp,         // [8][D_HID]
    const int* __restrict__ eidx,
    const float* __restrict__ s12,           // [N_TOK][2]
    float* __restrict__ out) {
    __shared__ __align__(16) short lds[4 * 2048 * 8];  // 128 KiB

    const int t512 = threadIdx.x;
    const int lane = t512 & 63;
    const int w    = t512 >> 6;
    const int wm   = w >> 2;
    const int wn   = w & 3;

    // XCD swizzle: each XCD owns bx pair (B slabs 2 MB -> L2-resident)
    const int bid = blockIdx.x;
    const int xcd = bid & 7;
    const int jb  = bid >> 3;
    const int bx  = xcd * 2 + (jb & 1);
    const int by  = jb >> 1;
    const int mbase = by * 256;
    const int nbase = bx * 128;

    const unsigned short* gA0 = xb  + ((size_t)by * 64) * 8192 + t512 * 8;
    const unsigned short* gB0 = wbT + ((size_t)bx * 64) * 8192 + t512 * 8;

    const int aks  = (lane >> 4) * 256;
    const int arow = wm * 128 + (lane & 15);
    const int brow = wn * 64 + (lane & 15);

    f32x4 acc[8][4];
#pragma unroll
    for (int mi = 0; mi < 8; ++mi)
#pragma unroll
        for (int ni = 0; ni < 4; ++ni) acc[mi][ni] = (f32x4){0.f, 0.f, 0.f, 0.f};

    bf16x8 bA[4], a0A[4], bB[4], a0B[4], a4[4];

    // prologue: stage tiles 0,1,2; vmcnt(4) retires tiles 0,1; read tile 0.
    STAGE_A(0, 0);    STAGE_B(0, 0);
    STAGE_A(2048, 1); STAGE_B(2048, 1);
    STAGE_A(4096, 2); STAGE_B(4096, 2);
    asm volatile("s_waitcnt vmcnt(4)" ::: "memory");
    __builtin_amdgcn_s_barrier();
    bA[0] = LDSV(1024 + aks + brow);      bA[1] = LDSV(1024 + aks + brow + 16);
    bA[2] = LDSV(1024 + aks + brow + 32); bA[3] = LDSV(1024 + aks + brow + 48);
    a0A[0] = LDSV(aks + arow);            a0A[1] = LDSV(aks + arow + 16);
    a0A[2] = LDSV(aks + arow + 32);       a0A[3] = LDSV(aks + arow + 48);

    for (int t = 0; t < 60; t += 2) {
        PH1(t, 1, a0A, bA);
        PH2(t, 1, "s_waitcnt vmcnt(4)", bB, a0B, bA);
        PH1(t + 1, 1, a0B, bB);
        PH2(t + 1, 1, "s_waitcnt vmcnt(4)", bA, a0A, bB);
    }
    PH1(60, 1, a0A, bA);
    PH2(60, 1, "s_waitcnt vmcnt(4)", bB, a0B, bA);
    PH1(61, 0, a0B, bB);
    PH2(61, 0, "s_waitcnt vmcnt(0)", bA, a0A, bB);
    PH1(62, 0, a0A, bA);
    PH2(62, 0, "s_waitcnt vmcnt(0)", bB, a0B, bA);
    // final tile 63 (B-set current)
    {
        const int rb = 3 * 2048;
        a4[0] = LDSV(rb + aks + arow + 64);
        a4[1] = LDSV(rb + aks + arow + 80);
        a4[2] = LDSV(rb + aks + arow + 96);
        a4[3] = LDSV(rb + aks + arow + 112);
        MF16(a0B, bB, 0)
        MF16(a4, bB, 4)
    }

    // -------- epilogue: combine experts through LDS (f32) --------
    __syncthreads();
    float* fl = (float*)lds;
    if (wn >= 2) {
        float* reg = fl + (wm * 2 + (wn - 2)) * 8192;   // [128][64]
#pragma unroll
        for (int mi = 0; mi < 8; ++mi)
#pragma unroll
            for (int ni = 0; ni < 4; ++ni)
#pragma unroll
                for (int j = 0; j < 4; ++j) {
                    int row_l = mi * 16 + ((lane >> 4) << 2) + j;
                    int col_l = ni * 16 + (lane & 15);
                    reg[row_l * 64 + col_l] = acc[mi][ni][j];
                }
    }
    __syncthreads();
    if (wn < 2) {
        const float* reg = fl + (wm * 2 + wn) * 8192;
        const int e0 = eidx[0], e1 = eidx[1];
        const float* bb0 = b_exp + (size_t)e0 * D_HID;
        const float* bb1 = b_exp + (size_t)e1 * D_HID;
        const float2* s12v = (const float2*)s12;
        int   cc[4];
        float b0c[4], b1c[4];
#pragma unroll
        for (int ni = 0; ni < 4; ++ni) {
            cc[ni]  = nbase + wn * 64 + ni * 16 + (lane & 15);
            b0c[ni] = bb0[cc[ni]];
            b1c[ni] = bb1[cc[ni]];
        }
#pragma unroll
        for (int mi = 0; mi < 8; ++mi)
#pragma unroll
            for (int j = 0; j < 4; ++j) {
                int row_l = mi * 16 + ((lane >> 4) << 2) + j;
                int r = mbase + wm * 128 + row_l;
                float2 s = s12v[r];
#pragma unroll
                for (int ni = 0; ni < 4; ++ni) {
                    float y1 = reg[row_l * 64 + ni * 16 + (lane & 15)];
                    out[(size_t)r * D_HID + cc[ni]] =
                        s.x * (acc[mi][ni][j] + b0c[ni]) + s.y * (y1 + b1c[ni]);
                }
            }
    }
}

// ---------------------------------------------------------------- launch --
extern "C" void kernel_launch(void* const* d_in, const int* in_sizes, int n_in,
                              void* d_out, int out_size, void* d_ws, size_t ws_size,
                              hipStream_t stream) {
    const float* x         = (const float*)d_in[0];
    const float* W_experts = (const float*)d_in[1];
    const float* b_experts = (const float*)d_in[2];
    const float* W_gate    = (const float*)d_in[3];
    const float* b_gate    = (const float*)d_in[4];
    float* out = (float*)d_out;

    char* ws = (char*)d_ws;
    float* s12  = (float*)ws;                                        // 128 KiB
    int*   eidx = (int*)(ws + 131072);
    unsigned short* xb  = (unsigned short*)(ws + 262144);            // 64 MiB
    unsigned short* wbT = (unsigned short*)(ws + 262144 + 67108864); // 16 MiB

    gate_kernel<<<N_TOK / 4, 256, 0, stream>>>(x, W_gate, b_gate, s12, eidx);
    xconv_kernel<<<4096, 256, 0, stream>>>(x, xb);
    wconv_kernel<<<dim3(32, 32, 2), 256, 0, stream>>>(W_experts, eidx, wbT);
    moe_gemm_kernel<<<1024, 512, 0, stream>>>(xb, wbT, b_experts, eidx, s12, out);
}